// Round 17
// baseline (46.762 us; speedup 1.0000x reference)
//
#include <hip/hip_runtime.h>
#include <hip/hip_bf16.h>

// B=4, T=4096, E=512, H=64. out fp32 [B,T,H].
#define Bn 4
#define Tn 4096
#define En 512
#define Hn 64
#define NEGINF -3e38f
// 0.125 (1/sqrt(64)) * log2(e): QK^T output lands in log2 domain
#define QSCALE 0.1803368801f

typedef __attribute__((ext_vector_type(8))) __bf16 bf16x8;
typedef __attribute__((ext_vector_type(4))) __bf16 bf16x4;
typedef __attribute__((ext_vector_type(4))) float f32x4;

#define MFMA16(a, b, c) __builtin_amdgcn_mfma_f32_16x16x32_bf16(a, b, c, 0, 0, 0)

__device__ __forceinline__ float bf2f(unsigned short u) {
    union { unsigned u; float f; } v; v.u = ((unsigned)u) << 16;
    return v.f;
}
__device__ __forceinline__ unsigned cvtpk(float a, float b) {
    unsigned d;
    asm("v_cvt_pk_bf16_f32 %0, %1, %2" : "=v"(d) : "v"(a), "v"(b));
    return d;
}
__device__ __forceinline__ unsigned short f2bf(float f) {
    union { float f; unsigned u; } v; v.f = f;
    unsigned r = v.u + 0x7fffu + ((v.u >> 16) & 1u);
    return (unsigned short)(r >> 16);
}
__device__ __forceinline__ float exp2fast(float x) {
    float r;
    asm("v_exp_f32 %0, %1" : "=v"(r) : "v"(x));
    return r;
}
// async global->LDS DMA, 16B per lane; lds dest is wave-uniform base + lane*16
__device__ __forceinline__ void gl16(const void* g, void* l) {
    __builtin_amdgcn_global_load_lds(
        (const __attribute__((address_space(1))) unsigned int*)g,
        (__attribute__((address_space(3))) unsigned int*)l, 16, 0, 0);
}

// ---------------- kernel 1: fused QKV projection (wcvt fused in) -------------
// 512 blocks x 32-row tiles (2 blocks/CU), dbuf LDS + T14 reg-staged prefetch
// (x AND W held as raw fp32 until the LDS-write phase), ONE barrier/step,
// unpadded XOR-swizzled tiles. W read directly from Wq/Wk/Wv fp32 (L2-hot,
// 400KB); matrix choice per staging chunk is compile-time (mat = c2>>1).
// q16 pre-scaled by QSCALE so attn's QK^T lands in log2 domain.
__launch_bounds__(256, 2)
__global__ void proj(const float* __restrict__ x, const float* __restrict__ Wq,
                     const float* __restrict__ Wk, const float* __restrict__ Wv,
                     unsigned short* __restrict__ q16, unsigned short* __restrict__ k16,
                     unsigned short* __restrict__ vt16) {
    __shared__ __align__(16) unsigned char plds[2][28672];  // [buf][A 4KB | W 24KB]
    const int tid = threadIdx.x;
    const int w = tid >> 6, lane = tid & 63, r = lane & 15, g = lane >> 4;
    const int row0 = blockIdx.x * 32;
    const int rsel = (w & 1) * 16, csel = (w >> 1) * 96;

    const int srow = tid >> 3, skc = (tid & 7) * 8;   // staging: row, k-offset
    const int sby = (tid & 7) * 16;                   // byte col in LDS row

    f32x4 acc[6];
#pragma unroll
    for (int i = 0; i < 6; ++i) acc[i] = (f32x4){0.f, 0.f, 0.f, 0.f};

    // prologue: stage k-step 0 into buf 0
    {
        const float4* xp = (const float4*)&x[(row0 + srow) * En + skc];
        float4 f0 = xp[0], f1 = xp[1];
        union { bf16x8 v; unsigned u32[4]; } t;
        t.u32[0] = cvtpk(f0.x, f0.y); t.u32[1] = cvtpk(f0.z, f0.w);
        t.u32[2] = cvtpk(f1.x, f1.y); t.u32[3] = cvtpk(f1.z, f1.w);
        *(bf16x8*)&plds[0][srow * 128 + (sby ^ ((srow & 7) << 4))] = t.v;
#pragma unroll
        for (int c2 = 0; c2 < 6; ++c2) {
            const float* Ws = (c2 < 2) ? Wq : ((c2 < 4) ? Wk : Wv);
            int wr = (c2 & 1) * 32 + srow;
            const float4* wp = (const float4*)&Ws[wr * En + skc];
            float4 w0 = wp[0], w1 = wp[1];
            union { bf16x8 v; unsigned u32[4]; } tw;
            tw.u32[0] = cvtpk(w0.x, w0.y); tw.u32[1] = cvtpk(w0.z, w0.w);
            tw.u32[2] = cvtpk(w1.x, w1.y); tw.u32[3] = cvtpk(w1.z, w1.w);
            int wrow = c2 * 32 + srow;
            *(bf16x8*)&plds[0][4096 + wrow * 128 + (sby ^ ((wrow & 7) << 4))] = tw.v;
        }
    }
    __syncthreads();

    for (int s = 0; s < 8; ++s) {
        const int pp = s & 1;
        const bool more = (s < 7);
        // T14: prefetch next k-step into regs (raw fp32 until write phase)
        float4 nf0, nf1;
        float4 nw0[6], nw1[6];
        if (more) {
            int k1 = (s + 1) * 64;
            const float4* xp = (const float4*)&x[(row0 + srow) * En + k1 + skc];
            nf0 = xp[0]; nf1 = xp[1];
#pragma unroll
            for (int c2 = 0; c2 < 6; ++c2) {
                const float* Ws = (c2 < 2) ? Wq : ((c2 < 4) ? Wk : Wv);
                int wr = (c2 & 1) * 32 + srow;
                const float4* wp = (const float4*)&Ws[wr * En + k1 + skc];
                nw0[c2] = wp[0]; nw1[c2] = wp[1];
            }
        }
        // compute from buf pp
        {
            const unsigned char* A = &plds[pp][0];
            const unsigned char* W = &plds[pp][4096];
            int arow = rsel + r, asw = (arow & 7) << 4;
            bf16x8 a0 = *(const bf16x8*)&A[arow * 128 + ((g * 16) ^ asw)];
            bf16x8 a1 = *(const bf16x8*)&A[arow * 128 + ((64 + g * 16) ^ asw)];
#pragma unroll
            for (int ct = 0; ct < 6; ++ct) {
                int wrow = csel + ct * 16 + r, wsw = (wrow & 7) << 4;
                bf16x8 b0 = *(const bf16x8*)&W[wrow * 128 + ((g * 16) ^ wsw)];
                bf16x8 b1 = *(const bf16x8*)&W[wrow * 128 + ((64 + g * 16) ^ wsw)];
                acc[ct] = MFMA16(a0, b0, acc[ct]);
                acc[ct] = MFMA16(a1, b1, acc[ct]);
            }
        }
        // write prefetched tile into buf pp^1, one barrier
        if (more) {
            unsigned char* D = &plds[pp ^ 1][0];
            union { bf16x8 v; unsigned u32[4]; } t;
            t.u32[0] = cvtpk(nf0.x, nf0.y); t.u32[1] = cvtpk(nf0.z, nf0.w);
            t.u32[2] = cvtpk(nf1.x, nf1.y); t.u32[3] = cvtpk(nf1.z, nf1.w);
            *(bf16x8*)&D[srow * 128 + (sby ^ ((srow & 7) << 4))] = t.v;
#pragma unroll
            for (int c2 = 0; c2 < 6; ++c2) {
                union { bf16x8 v; unsigned u32[4]; } tw;
                tw.u32[0] = cvtpk(nw0[c2].x, nw0[c2].y); tw.u32[1] = cvtpk(nw0[c2].z, nw0[c2].w);
                tw.u32[2] = cvtpk(nw1[c2].x, nw1[c2].y); tw.u32[3] = cvtpk(nw1[c2].z, nw1[c2].w);
                int wrow = c2 * 32 + srow;
                *(bf16x8*)&D[4096 + wrow * 128 + (sby ^ ((wrow & 7) << 4))] = tw.v;
            }
        }
        __syncthreads();
    }
    // epilogue: C layout col = lane&15, row = (lane>>4)*4 + reg
#pragma unroll
    for (int ct = 0; ct < 6; ++ct) {
        int n = csel + ct * 16 + r;
#pragma unroll
        for (int reg = 0; reg < 4; ++reg) {
            int gr = row0 + rsel + g * 4 + reg;
            if (n < 64) {
                q16[gr * 64 + n] = f2bf(acc[ct][reg] * QSCALE);
            } else if (n < 128) {
                k16[gr * 64 + (n - 64)] = f2bf(acc[ct][reg]);
            } else {
                int h = n - 128; int bb = gr >> 12; int t = gr & 4095;
                vt16[((bb * 64 + h) << 12) + t] = f2bf(acc[ct][reg]);
            }
        }
    }
}

// ---------------- kernel 2: attention partials (5 blocks/CU, 160KB LDS) ------
// 1280 blocks x 256 thr (4 q-split waves x 16 q-rows = 64-q tile).
// bid -> page=bid>>8 (0..4), idx=bid&255: s5=idx>>3, b=(idx>>1)&3, q1=idx&1.
// pages 0-2: jt=63-s5 (long), piece = page+3*q1 of SIX kv-sixths;
// pages 3-4: jt=s5 (short), piece = (page-3)+2*q1 of FOUR kv-quarters.
// Per-CU = (64-s)/2 + (s+1)/2 = uniform 32.5 tiles; 5 independent blocks/CU
// (5 x 32KB = exactly 160KB LDS), 20 waves/CU. launch_bounds(256,5): VGPR<=102.
// Staging via async global_load_lds with pre-swizzled global source; fixed-m
// log2 softmax (no cross-lane ops). Partials (o bf16, l f32) -> ws by piece.
__launch_bounds__(256, 5)
__global__ void attnp(const unsigned short* __restrict__ q16, const unsigned short* __restrict__ k16,
                      const unsigned short* __restrict__ vt16,
                      unsigned short* __restrict__ po, float* __restrict__ lp) {
    __shared__ __align__(16) unsigned char lds[2][16384];  // [buf][K 8KB | V 8KB]

    const int tid = threadIdx.x;
    const int w = tid >> 6, lane = tid & 63, r = lane & 15, g = lane >> 4;
    const int bid = blockIdx.x;
    const int page = bid >> 8, idx = bid & 255;
    const int s5 = idx >> 3, b = (idx >> 1) & 3, q1 = idx & 1;
    int jt, piece, t0, tEnd;
    if (page < 3) {
        jt = 63 - s5;
        int nt = jt + 1;
        piece = page + 3 * q1;                       // 0..5
        t0 = (piece * nt) / 6; tEnd = ((piece + 1) * nt) / 6;
    } else {
        jt = s5;
        int nt = jt + 1;
        piece = (page - 3) + 2 * q1;                 // 0..3
        t0 = (piece * nt) / 4; tEnd = ((piece + 1) * nt) / 4;
    }
    const size_t kbase = (size_t)b * Tn;
    const int q0 = jt * 64;
    const int wq0 = q0 + w * 16;

    const unsigned short* Kb = k16 + kbase * 64;
    const unsigned short* Vb = vt16 + ((size_t)(b * 64) << 12);

    // staging geometry: wave w owns chunks w*4..w*4+3 (1KB each: 8 rows x 128B)
    const int srl = lane >> 3, scb = (lane & 7) * 16;

    // Q B-frags (pre-scaled into log2 domain)
    bf16x8 bq0, bq1;
    {
        const unsigned short* qp = &q16[(kbase + wq0 + r) * 64 + g * 8];
        bq0 = *(const bf16x8*)qp;
        bq1 = *(const bf16x8*)(qp + 32);
    }

    f32x4 o[4];
#pragma unroll
    for (int i = 0; i < 4; ++i) o[i] = (f32x4){0.f, 0.f, 0.f, 0.f};
    float l_ = 0.f;

    // prologue: stage tile t0 into buf 0 (async DMA)
    if (tEnd > t0) {
        int kv0 = t0 * 64;
#pragma unroll
        for (int i = 0; i < 4; ++i) {
            int cc = w * 4 + i;
            if (cc < 8) {
                int row = cc * 8 + srl, sw = (row & 7) << 4;
                gl16((const char*)Kb + (size_t)(kv0 + row) * 128 + (scb ^ sw),
                     &lds[0][cc * 1024]);
            } else {
                int h = (cc - 8) * 8 + srl, sw = (h & 7) << 4;
                gl16((const char*)Vb + (size_t)h * 8192 + (size_t)kv0 * 2 + (scb ^ sw),
                     &lds[0][cc * 1024]);
            }
        }
    }
    __syncthreads();

    int pp = 0;
    for (int it = t0; it < tEnd; ++it, pp ^= 1) {
        const bool more = (it + 1 < tEnd);
        // async-stage next tile into buf pp^1
        if (more) {
            int nkv = (it + 1) * 64;
#pragma unroll
            for (int i = 0; i < 4; ++i) {
                int cc = w * 4 + i;
                if (cc < 8) {
                    int row = cc * 8 + srl, sw = (row & 7) << 4;
                    gl16((const char*)Kb + (size_t)(nkv + row) * 128 + (scb ^ sw),
                         &lds[pp ^ 1][cc * 1024]);
                } else {
                    int h = (cc - 8) * 8 + srl, sw = (h & 7) << 4;
                    gl16((const char*)Vb + (size_t)h * 8192 + (size_t)nkv * 2 + (scb ^ sw),
                         &lds[pp ^ 1][cc * 1024]);
                }
            }
        }
        const int kv0 = it * 64;
        if (kv0 <= wq0 + 15) {                      // wave-level causal skip
            const unsigned char* K = &lds[pp][0];
            const unsigned char* V = &lds[pp][8192];
            f32x4 s4[4];
            __builtin_amdgcn_s_setprio(1);
#pragma unroll
            for (int ct = 0; ct < 4; ++ct) {
                int row = ct * 16 + r;
                int base = row * 128, sw = (row & 7) << 4;
                bf16x8 ak0 = *(const bf16x8*)&K[base + ((g * 16) ^ sw)];
                bf16x8 ak1 = *(const bf16x8*)&K[base + ((64 + g * 16) ^ sw)];
                f32x4 t = (f32x4){0.f, 0.f, 0.f, 0.f};
                t = MFMA16(ak0, bq0, t);
                t = MFMA16(ak1, bq1, t);
                s4[ct] = t;
            }
            __builtin_amdgcn_s_setprio(0);
            // diagonal masking (log2 domain: no scale mul)
            if (kv0 + 63 > wq0) {
                int qq = wq0 + r;
#pragma unroll
                for (int ct = 0; ct < 4; ++ct)
#pragma unroll
                    for (int reg = 0; reg < 4; ++reg) {
                        int kv = kv0 + ct * 16 + g * 4 + reg;
                        if (kv > qq) s4[ct][reg] = NEGINF;
                    }
            }
            // fixed-m: P = exp2(S); per-lane l partial; no cross-lane ops
#pragma unroll
            for (int ct = 0; ct < 4; ++ct)
#pragma unroll
                for (int reg = 0; reg < 4; ++reg)
                    s4[ct][reg] = exp2fast(s4[ct][reg]);
            l_ += ((s4[0][0] + s4[0][1]) + (s4[0][2] + s4[0][3])) +
                  ((s4[1][0] + s4[1][1]) + (s4[1][2] + s4[1][3])) +
                  ((s4[2][0] + s4[2][1]) + (s4[2][2] + s4[2][3])) +
                  ((s4[3][0] + s4[3][1]) + (s4[3][2] + s4[3][3]));
            union { bf16x8 v; unsigned u32[4]; } pk[2];
#pragma unroll
            for (int kf = 0; kf < 2; ++kf) {
                pk[kf].u32[0] = cvtpk(s4[kf * 2][0], s4[kf * 2][1]);
                pk[kf].u32[1] = cvtpk(s4[kf * 2][2], s4[kf * 2][3]);
                pk[kf].u32[2] = cvtpk(s4[kf * 2 + 1][0], s4[kf * 2 + 1][1]);
                pk[kf].u32[3] = cvtpk(s4[kf * 2 + 1][2], s4[kf * 2 + 1][3]);
            }
            // PV: V B-frag with matching k-bijection, swizzled LDS reads
            __builtin_amdgcn_s_setprio(1);
#pragma unroll
            for (int cth = 0; cth < 4; ++cth) {
                int h = cth * 16 + r;
                int vb = h * 128, sw2 = (h & 7) << 4;
#pragma unroll
                for (int kf = 0; kf < 2; ++kf) {
                    int off = kf * 64 + g * 8;
                    union { bf16x8 v; bf16x4 h4[2]; } vv;
                    vv.h4[0] = *(const bf16x4*)&V[vb + (off ^ sw2)];
                    vv.h4[1] = *(const bf16x4*)&V[vb + ((off + 32) ^ sw2)];
                    o[cth] = MFMA16(pk[kf].v, vv.v, o[cth]);
                }
            }
            __builtin_amdgcn_s_setprio(0);
        }
        __syncthreads();   // drains DMA (vmcnt) + all reads of buf pp done
    }

    // ---- write partials (always; empty piece -> zeros) ----
    const size_t qb = (size_t)piece * 16384 + b * 4096;
#pragma unroll
    for (int cth = 0; cth < 4; ++cth)
#pragma unroll
        for (int reg = 0; reg < 4; ++reg)
            po[(qb + wq0 + g * 4 + reg) * 64 + cth * 16 + r] = f2bf(o[cth][reg]);
    lp[(qb + wq0 + r) * 4 + g] = l_;
}

// ---------------- kernel 3: merge piece partials + normalize ----------------
// 512 blocks x 256 thr; thread -> (q, 8 cols). Long-jt rows (tloc>=32) have 6
// slices, short rows 4 (unwritten slices never read -> poison-safe).
__global__ void merge(const unsigned short* __restrict__ po, const float* __restrict__ lp,
                      float* __restrict__ out) {
    int t = blockIdx.x * 256 + threadIdx.x;        // 0..131071
    int q = t >> 3, c8 = (t & 7) * 8;
    int tloc = (q & 4095) >> 6;
    int ns = (tloc >= 32) ? 6 : 4;
    float L = 0.f;
    for (int c = 0; c < ns; ++c)
#pragma unroll
        for (int gg = 0; gg < 4; ++gg)
            L += lp[((size_t)c * 16384 + q) * 4 + gg];
    float inv = 1.0f / L;
    float acc[8] = {0.f, 0.f, 0.f, 0.f, 0.f, 0.f, 0.f, 0.f};
    for (int c = 0; c < ns; ++c) {
        union { uint4 v; unsigned short u[8]; } ld;
        ld.v = *(const uint4*)&po[((size_t)c * 16384 + q) * 64 + c8];
#pragma unroll
        for (int j = 0; j < 8; ++j) acc[j] += bf2f(ld.u[j]);
    }
    float4* op = (float4*)&out[(size_t)q * 64 + c8];
    op[0] = (float4){acc[0] * inv, acc[1] * inv, acc[2] * inv, acc[3] * inv};
    op[1] = (float4){acc[4] * inv, acc[5] * inv, acc[6] * inv, acc[7] * inv};
}

extern "C" void kernel_launch(void* const* d_in, const int* in_sizes, int n_in,
                              void* d_out, int out_size, void* d_ws, size_t ws_size,
                              hipStream_t stream) {
    const float* x  = (const float*)d_in[0];
    const float* Wq = (const float*)d_in[1];
    const float* Wk = (const float*)d_in[2];
    const float* Wv = (const float*)d_in[3];
    float* out = (float*)d_out;
    char* ws = (char*)d_ws;

    unsigned short* q16 = (unsigned short*)ws;                  // 2 MiB
    unsigned short* k16 = (unsigned short*)(ws + 2097152);      // 2 MiB
    unsigned short* v16 = (unsigned short*)(ws + 4194304);      // 2 MiB
    unsigned short* po  = (unsigned short*)(ws + 6291456);      // 6*16384*64*2 = 12 MiB
    float*          lp  = (float*)(ws + 18874368);              // 6*16384*4*4  = 1.5 MiB
    // total ws use: ~19.5 MiB

    hipLaunchKernelGGL(proj, dim3(512), dim3(256), 0, stream, x, Wq, Wk, Wv, q16, k16, v16);
    hipLaunchKernelGGL(attnp, dim3(1280), dim3(256), 0, stream, q16, k16, v16, po, lp);
    hipLaunchKernelGGL(merge, dim3(512), dim3(256), 0, stream, po, lp, out);
}

// Round 18
// 44.377 us; speedup vs baseline: 1.0538x; 1.0538x over previous
//
#include <hip/hip_runtime.h>
#include <hip/hip_bf16.h>

// B=4, T=4096, E=512, H=64. out fp32 [B,T,H].
#define Bn 4
#define Tn 4096
#define En 512
#define Hn 64
#define NEGINF -3e38f
// 0.125 (1/sqrt(64)) * log2(e): QK^T output lands in log2 domain
#define QSCALE 0.1803368801f

typedef __attribute__((ext_vector_type(8))) __bf16 bf16x8;
typedef __attribute__((ext_vector_type(4))) __bf16 bf16x4;
typedef __attribute__((ext_vector_type(4))) float f32x4;

#define MFMA16(a, b, c) __builtin_amdgcn_mfma_f32_16x16x32_bf16(a, b, c, 0, 0, 0)

__device__ __forceinline__ float bf2f(unsigned short u) {
    union { unsigned u; float f; } v; v.u = ((unsigned)u) << 16;
    return v.f;
}
__device__ __forceinline__ unsigned cvtpk(float a, float b) {
    unsigned d;
    asm("v_cvt_pk_bf16_f32 %0, %1, %2" : "=v"(d) : "v"(a), "v"(b));
    return d;
}
__device__ __forceinline__ unsigned short f2bf(float f) {
    union { float f; unsigned u; } v; v.f = f;
    unsigned r = v.u + 0x7fffu + ((v.u >> 16) & 1u);
    return (unsigned short)(r >> 16);
}
__device__ __forceinline__ float exp2fast(float x) {
    float r;
    asm("v_exp_f32 %0, %1" : "=v"(r) : "v"(x));
    return r;
}
// async global->LDS DMA, 16B per lane; lds dest is wave-uniform base + lane*16
__device__ __forceinline__ void gl16(const void* g, void* l) {
    __builtin_amdgcn_global_load_lds(
        (const __attribute__((address_space(1))) unsigned int*)g,
        (__attribute__((address_space(3))) unsigned int*)l, 16, 0, 0);
}

// ---------------- kernel 1: fused QKV projection (wcvt fused in) -------------
// 512 blocks x 32-row tiles (2 blocks/CU), dbuf LDS + T14 reg-staged prefetch,
// ONE barrier/step, unpadded XOR-swizzled tiles. W read directly from fp32.
// q16 pre-scaled by QSCALE so attn's QK^T lands in log2 domain.
__launch_bounds__(256, 2)
__global__ void proj(const float* __restrict__ x, const float* __restrict__ Wq,
                     const float* __restrict__ Wk, const float* __restrict__ Wv,
                     unsigned short* __restrict__ q16, unsigned short* __restrict__ k16,
                     unsigned short* __restrict__ vt16) {
    __shared__ __align__(16) unsigned char plds[2][28672];  // [buf][A 4KB | W 24KB]
    const int tid = threadIdx.x;
    const int w = tid >> 6, lane = tid & 63, r = lane & 15, g = lane >> 4;
    const int row0 = blockIdx.x * 32;
    const int rsel = (w & 1) * 16, csel = (w >> 1) * 96;

    const int srow = tid >> 3, skc = (tid & 7) * 8;   // staging: row, k-offset
    const int sby = (tid & 7) * 16;                   // byte col in LDS row

    f32x4 acc[6];
#pragma unroll
    for (int i = 0; i < 6; ++i) acc[i] = (f32x4){0.f, 0.f, 0.f, 0.f};

    // prologue: stage k-step 0 into buf 0
    {
        const float4* xp = (const float4*)&x[(row0 + srow) * En + skc];
        float4 f0 = xp[0], f1 = xp[1];
        union { bf16x8 v; unsigned u32[4]; } t;
        t.u32[0] = cvtpk(f0.x, f0.y); t.u32[1] = cvtpk(f0.z, f0.w);
        t.u32[2] = cvtpk(f1.x, f1.y); t.u32[3] = cvtpk(f1.z, f1.w);
        *(bf16x8*)&plds[0][srow * 128 + (sby ^ ((srow & 7) << 4))] = t.v;
#pragma unroll
        for (int c2 = 0; c2 < 6; ++c2) {
            const float* Ws = (c2 < 2) ? Wq : ((c2 < 4) ? Wk : Wv);
            int wr = (c2 & 1) * 32 + srow;
            const float4* wp = (const float4*)&Ws[wr * En + skc];
            float4 w0 = wp[0], w1 = wp[1];
            union { bf16x8 v; unsigned u32[4]; } tw;
            tw.u32[0] = cvtpk(w0.x, w0.y); tw.u32[1] = cvtpk(w0.z, w0.w);
            tw.u32[2] = cvtpk(w1.x, w1.y); tw.u32[3] = cvtpk(w1.z, w1.w);
            int wrow = c2 * 32 + srow;
            *(bf16x8*)&plds[0][4096 + wrow * 128 + (sby ^ ((wrow & 7) << 4))] = tw.v;
        }
    }
    __syncthreads();

    for (int s = 0; s < 8; ++s) {
        const int pp = s & 1;
        const bool more = (s < 7);
        // T14: prefetch next k-step into regs (raw fp32 until write phase)
        float4 nf0, nf1;
        float4 nw0[6], nw1[6];
        if (more) {
            int k1 = (s + 1) * 64;
            const float4* xp = (const float4*)&x[(row0 + srow) * En + k1 + skc];
            nf0 = xp[0]; nf1 = xp[1];
#pragma unroll
            for (int c2 = 0; c2 < 6; ++c2) {
                const float* Ws = (c2 < 2) ? Wq : ((c2 < 4) ? Wk : Wv);
                int wr = (c2 & 1) * 32 + srow;
                const float4* wp = (const float4*)&Ws[wr * En + k1 + skc];
                nw0[c2] = wp[0]; nw1[c2] = wp[1];
            }
        }
        // compute from buf pp
        {
            const unsigned char* A = &plds[pp][0];
            const unsigned char* W = &plds[pp][4096];
            int arow = rsel + r, asw = (arow & 7) << 4;
            bf16x8 a0 = *(const bf16x8*)&A[arow * 128 + ((g * 16) ^ asw)];
            bf16x8 a1 = *(const bf16x8*)&A[arow * 128 + ((64 + g * 16) ^ asw)];
#pragma unroll
            for (int ct = 0; ct < 6; ++ct) {
                int wrow = csel + ct * 16 + r, wsw = (wrow & 7) << 4;
                bf16x8 b0 = *(const bf16x8*)&W[wrow * 128 + ((g * 16) ^ wsw)];
                bf16x8 b1 = *(const bf16x8*)&W[wrow * 128 + ((64 + g * 16) ^ wsw)];
                acc[ct] = MFMA16(a0, b0, acc[ct]);
                acc[ct] = MFMA16(a1, b1, acc[ct]);
            }
        }
        // write prefetched tile into buf pp^1, one barrier
        if (more) {
            unsigned char* D = &plds[pp ^ 1][0];
            union { bf16x8 v; unsigned u32[4]; } t;
            t.u32[0] = cvtpk(nf0.x, nf0.y); t.u32[1] = cvtpk(nf0.z, nf0.w);
            t.u32[2] = cvtpk(nf1.x, nf1.y); t.u32[3] = cvtpk(nf1.z, nf1.w);
            *(bf16x8*)&D[srow * 128 + (sby ^ ((srow & 7) << 4))] = t.v;
#pragma unroll
            for (int c2 = 0; c2 < 6; ++c2) {
                union { bf16x8 v; unsigned u32[4]; } tw;
                tw.u32[0] = cvtpk(nw0[c2].x, nw0[c2].y); tw.u32[1] = cvtpk(nw0[c2].z, nw0[c2].w);
                tw.u32[2] = cvtpk(nw1[c2].x, nw1[c2].y); tw.u32[3] = cvtpk(nw1[c2].z, nw1[c2].w);
                int wrow = c2 * 32 + srow;
                *(bf16x8*)&D[4096 + wrow * 128 + (sby ^ ((wrow & 7) << 4))] = tw.v;
            }
        }
        __syncthreads();
    }
    // epilogue: C layout col = lane&15, row = (lane>>4)*4 + reg
#pragma unroll
    for (int ct = 0; ct < 6; ++ct) {
        int n = csel + ct * 16 + r;
#pragma unroll
        for (int reg = 0; reg < 4; ++reg) {
            int gr = row0 + rsel + g * 4 + reg;
            if (n < 64) {
                q16[gr * 64 + n] = f2bf(acc[ct][reg] * QSCALE);
            } else if (n < 128) {
                k16[gr * 64 + (n - 64)] = f2bf(acc[ct][reg]);
            } else {
                int h = n - 128; int bb = gr >> 12; int t = gr & 4095;
                vt16[((bb * 64 + h) << 12) + t] = f2bf(acc[ct][reg]);
            }
        }
    }
}

// ---------------- kernel 2: attention partials (T4 counted-wait schedule) ----
// 1024 blocks x 256 thr (4 q-split waves x 16 q-rows = 64-q tile); r16 grid:
// k=bid>>8, idx=bid&255: s5=idx>>3, b=(idx>>1)&3, q1=idx&1; jt=(k&1)?s5:63-s5;
// quarter=((k>>1)<<1)|q1 -> 4 independent blocks/CU, uniform ~33 tiles/CU.
// NEW (T4/m218): per iter {s_waitcnt vmcnt(0); raw s_barrier; issue next-tile
// DMA; compute} -- the wait covers only the CURRENT tile's DMA (landed during
// the previous compute); next-tile DMA stays in flight across compute. This
// replaces __syncthreads(), whose implicit vmcnt(0) drained the prefetch.
// Safety: DMA(n+1) -> buf (n+1)&1 whose tenant (n-1) was consumed before the
// barrier all waves crossed; per-wave vmcnt(0)+barrier => all chunks resident.
__launch_bounds__(256, 4)
__global__ void attnp(const unsigned short* __restrict__ q16, const unsigned short* __restrict__ k16,
                      const unsigned short* __restrict__ vt16,
                      unsigned short* __restrict__ po, float* __restrict__ lp) {
    __shared__ __align__(16) unsigned char lds[2][16384];  // [buf][K 8KB | V 8KB]

    const int tid = threadIdx.x;
    const int w = tid >> 6, lane = tid & 63, r = lane & 15, g = lane >> 4;
    const int bid = blockIdx.x;
    const int k_ = bid >> 8, idx = bid & 255;
    const int s5 = idx >> 3, b = (idx >> 1) & 3, q1 = idx & 1;
    const int jt = (k_ & 1) ? s5 : 63 - s5;
    const int quarter = ((k_ >> 1) << 1) | q1;
    const size_t kbase = (size_t)b * Tn;
    const int q0 = jt * 64;
    const int nt = jt + 1;                          // total 64-kv tiles
    const int t0 = (quarter * nt) >> 2;
    const int tEnd = ((quarter + 1) * nt) >> 2;
    const int wq0 = q0 + w * 16;

    const unsigned short* Kb = k16 + kbase * 64;
    const unsigned short* Vb = vt16 + ((size_t)(b * 64) << 12);

    // staging geometry: wave w owns chunks w*4..w*4+3 (1KB each: 8 rows x 128B)
    const int srl = lane >> 3, scb = (lane & 7) * 16;

    // Q B-frags (pre-scaled into log2 domain)
    bf16x8 bq0, bq1;
    {
        const unsigned short* qp = &q16[(kbase + wq0 + r) * 64 + g * 8];
        bq0 = *(const bf16x8*)qp;
        bq1 = *(const bf16x8*)(qp + 32);
    }

    f32x4 o[4];
#pragma unroll
    for (int i = 0; i < 4; ++i) o[i] = (f32x4){0.f, 0.f, 0.f, 0.f};
    float l_ = 0.f;

    // prologue: issue DMA for tile t0 into buf t0&1
    if (tEnd > t0) {
        int kv0 = t0 * 64;
        unsigned char* D = &lds[t0 & 1][0];
#pragma unroll
        for (int i = 0; i < 4; ++i) {
            int cc = w * 4 + i;
            if (cc < 8) {
                int row = cc * 8 + srl, sw = (row & 7) << 4;
                gl16((const char*)Kb + (size_t)(kv0 + row) * 128 + (scb ^ sw), D + cc * 1024);
            } else {
                int h = (cc - 8) * 8 + srl, sw = (h & 7) << 4;
                gl16((const char*)Vb + (size_t)h * 8192 + (size_t)kv0 * 2 + (scb ^ sw), D + cc * 1024);
            }
        }
    }

    for (int it = t0; it < tEnd; ++it) {
        const int pp = it & 1;
        // T4: wait only for the current tile's DMA (in flight since last iter),
        // then raw barrier (no implicit drain of anything newer).
        asm volatile("s_waitcnt vmcnt(0)" ::: "memory");
        __builtin_amdgcn_s_barrier();
        __builtin_amdgcn_sched_barrier(0);
        // issue next-tile DMA; stays in flight across this iter's compute
        if (it + 1 < tEnd) {
            int nkv = (it + 1) * 64;
            unsigned char* D = &lds[pp ^ 1][0];
#pragma unroll
            for (int i = 0; i < 4; ++i) {
                int cc = w * 4 + i;
                if (cc < 8) {
                    int row = cc * 8 + srl, sw = (row & 7) << 4;
                    gl16((const char*)Kb + (size_t)(nkv + row) * 128 + (scb ^ sw), D + cc * 1024);
                } else {
                    int h = (cc - 8) * 8 + srl, sw = (h & 7) << 4;
                    gl16((const char*)Vb + (size_t)h * 8192 + (size_t)nkv * 2 + (scb ^ sw), D + cc * 1024);
                }
            }
        }
        const int kv0 = it * 64;
        if (kv0 <= wq0 + 15) {                      // wave-level causal skip
            const unsigned char* K = &lds[pp][0];
            const unsigned char* V = &lds[pp][8192];
            f32x4 s4[4];
            __builtin_amdgcn_s_setprio(1);
#pragma unroll
            for (int ct = 0; ct < 4; ++ct) {
                int row = ct * 16 + r;
                int base = row * 128, sw = (row & 7) << 4;
                bf16x8 ak0 = *(const bf16x8*)&K[base + ((g * 16) ^ sw)];
                bf16x8 ak1 = *(const bf16x8*)&K[base + ((64 + g * 16) ^ sw)];
                f32x4 t = (f32x4){0.f, 0.f, 0.f, 0.f};
                t = MFMA16(ak0, bq0, t);
                t = MFMA16(ak1, bq1, t);
                s4[ct] = t;
            }
            __builtin_amdgcn_s_setprio(0);
            // diagonal masking (log2 domain: no scale mul)
            if (kv0 + 63 > wq0) {
                int qq = wq0 + r;
#pragma unroll
                for (int ct = 0; ct < 4; ++ct)
#pragma unroll
                    for (int reg = 0; reg < 4; ++reg) {
                        int kv = kv0 + ct * 16 + g * 4 + reg;
                        if (kv > qq) s4[ct][reg] = NEGINF;
                    }
            }
            // fixed-m: P = exp2(S); per-lane l partial; no cross-lane ops
#pragma unroll
            for (int ct = 0; ct < 4; ++ct)
#pragma unroll
                for (int reg = 0; reg < 4; ++reg)
                    s4[ct][reg] = exp2fast(s4[ct][reg]);
            l_ += ((s4[0][0] + s4[0][1]) + (s4[0][2] + s4[0][3])) +
                  ((s4[1][0] + s4[1][1]) + (s4[1][2] + s4[1][3])) +
                  ((s4[2][0] + s4[2][1]) + (s4[2][2] + s4[2][3])) +
                  ((s4[3][0] + s4[3][1]) + (s4[3][2] + s4[3][3]));
            union { bf16x8 v; unsigned u32[4]; } pk[2];
#pragma unroll
            for (int kf = 0; kf < 2; ++kf) {
                pk[kf].u32[0] = cvtpk(s4[kf * 2][0], s4[kf * 2][1]);
                pk[kf].u32[1] = cvtpk(s4[kf * 2][2], s4[kf * 2][3]);
                pk[kf].u32[2] = cvtpk(s4[kf * 2 + 1][0], s4[kf * 2 + 1][1]);
                pk[kf].u32[3] = cvtpk(s4[kf * 2 + 1][2], s4[kf * 2 + 1][3]);
            }
            // PV: V B-frag with matching k-bijection, swizzled LDS reads
            __builtin_amdgcn_s_setprio(1);
#pragma unroll
            for (int cth = 0; cth < 4; ++cth) {
                int h = cth * 16 + r;
                int vb = h * 128, sw2 = (h & 7) << 4;
#pragma unroll
                for (int kf = 0; kf < 2; ++kf) {
                    int off = kf * 64 + g * 8;
                    union { bf16x8 v; bf16x4 h4[2]; } vv;
                    vv.h4[0] = *(const bf16x4*)&V[vb + (off ^ sw2)];
                    vv.h4[1] = *(const bf16x4*)&V[vb + ((off + 32) ^ sw2)];
                    o[cth] = MFMA16(pk[kf].v, vv.v, o[cth]);
                }
            }
            __builtin_amdgcn_s_setprio(0);
        }
    }

    // ---- write partials (always; empty quarter -> zeros) ----
    const size_t qb = (size_t)quarter * 16384 + b * 4096;
#pragma unroll
    for (int cth = 0; cth < 4; ++cth)
#pragma unroll
        for (int reg = 0; reg < 4; ++reg)
            po[(qb + wq0 + g * 4 + reg) * 64 + cth * 16 + r] = f2bf(o[cth][reg]);
    lp[(qb + wq0 + r) * 4 + g] = l_;
}

// ---------------- kernel 3: merge 4 kv-quarter partials + normalize ----------
// 512 blocks x 256 thr; thread -> (q, 8 cols): 16B po loads, float4x2 store.
__global__ void merge(const unsigned short* __restrict__ po, const float* __restrict__ lp,
                      float* __restrict__ out) {
    int t = blockIdx.x * 256 + threadIdx.x;        // 0..131071
    int q = t >> 3, c8 = (t & 7) * 8;
    float L = 0.f;
#pragma unroll
    for (int c = 0; c < 4; ++c)
#pragma unroll
        for (int gg = 0; gg < 4; ++gg)
            L += lp[((size_t)c * 16384 + q) * 4 + gg];
    float inv = 1.0f / L;
    float acc[8] = {0.f, 0.f, 0.f, 0.f, 0.f, 0.f, 0.f, 0.f};
#pragma unroll
    for (int c = 0; c < 4; ++c) {
        union { uint4 v; unsigned short u[8]; } ld;
        ld.v = *(const uint4*)&po[((size_t)c * 16384 + q) * 64 + c8];
#pragma unroll
        for (int j = 0; j < 8; ++j) acc[j] += bf2f(ld.u[j]);
    }
    float4* op = (float4*)&out[(size_t)q * 64 + c8];
    op[0] = (float4){acc[0] * inv, acc[1] * inv, acc[2] * inv, acc[3] * inv};
    op[1] = (float4){acc[4] * inv, acc[5] * inv, acc[6] * inv, acc[7] * inv};
}

extern "C" void kernel_launch(void* const* d_in, const int* in_sizes, int n_in,
                              void* d_out, int out_size, void* d_ws, size_t ws_size,
                              hipStream_t stream) {
    const float* x  = (const float*)d_in[0];
    const float* Wq = (const float*)d_in[1];
    const float* Wk = (const float*)d_in[2];
    const float* Wv = (const float*)d_in[3];
    float* out = (float*)d_out;
    char* ws = (char*)d_ws;

    unsigned short* q16 = (unsigned short*)ws;                  // 2 MiB
    unsigned short* k16 = (unsigned short*)(ws + 2097152);      // 2 MiB
    unsigned short* v16 = (unsigned short*)(ws + 4194304);      // 2 MiB
    unsigned short* po  = (unsigned short*)(ws + 6291456);      // 4*16384*64*2 = 8 MiB
    float*          lp  = (float*)(ws + 14680064);              // 4*16384*4*4  = 1 MiB
    // total ws use: ~15.7 MiB

    hipLaunchKernelGGL(proj, dim3(512), dim3(256), 0, stream, x, Wq, Wk, Wv, q16, k16, v16);
    hipLaunchKernelGGL(attnp, dim3(1024), dim3(256), 0, stream, q16, k16, v16, po, lp);
    hipLaunchKernelGGL(merge, dim3(512), dim3(256), 0, stream, po, lp, out);
}

// Round 19
// 42.424 us; speedup vs baseline: 1.1023x; 1.0460x over previous
//
#include <hip/hip_runtime.h>
#include <hip/hip_bf16.h>

// B=4, T=4096, E=512, H=64. out fp32 [B,T,H].
#define Bn 4
#define Tn 4096
#define En 512
#define Hn 64
#define NEGINF -3e38f
// 0.125 (1/sqrt(64)) * log2(e): QK^T output lands in log2 domain
#define QSCALE 0.1803368801f

typedef __attribute__((ext_vector_type(8))) __bf16 bf16x8;
typedef __attribute__((ext_vector_type(4))) __bf16 bf16x4;
typedef __attribute__((ext_vector_type(4))) float f32x4;

#define MFMA16(a, b, c) __builtin_amdgcn_mfma_f32_16x16x32_bf16(a, b, c, 0, 0, 0)

__device__ __forceinline__ float bf2f(unsigned short u) {
    union { unsigned u; float f; } v; v.u = ((unsigned)u) << 16;
    return v.f;
}
__device__ __forceinline__ unsigned cvtpk(float a, float b) {
    unsigned d;
    asm("v_cvt_pk_bf16_f32 %0, %1, %2" : "=v"(d) : "v"(a), "v"(b));
    return d;
}
__device__ __forceinline__ unsigned short f2bf(float f) {
    union { float f; unsigned u; } v; v.f = f;
    unsigned r = v.u + 0x7fffu + ((v.u >> 16) & 1u);
    return (unsigned short)(r >> 16);
}
__device__ __forceinline__ float exp2fast(float x) {
    float r;
    asm("v_exp_f32 %0, %1" : "=v"(r) : "v"(x));
    return r;
}
// async global->LDS DMA, 16B per lane; lds dest is wave-uniform base + lane*16
__device__ __forceinline__ void gl16(const void* g, void* l) {
    __builtin_amdgcn_global_load_lds(
        (const __attribute__((address_space(1))) unsigned int*)g,
        (__attribute__((address_space(3))) unsigned int*)l, 16, 0, 0);
}

// ---------------- kernel 1: fused QKV projection (wcvt fused in) -------------
// 512 blocks x 32-row tiles (2 blocks/CU), dbuf LDS + T14 reg-staged prefetch,
// ONE barrier/step, unpadded XOR-swizzled tiles. W read directly from fp32.
// q16 pre-scaled by QSCALE so attn's QK^T lands in log2 domain.
__launch_bounds__(256, 2)
__global__ void proj(const float* __restrict__ x, const float* __restrict__ Wq,
                     const float* __restrict__ Wk, const float* __restrict__ Wv,
                     unsigned short* __restrict__ q16, unsigned short* __restrict__ k16,
                     unsigned short* __restrict__ vt16) {
    __shared__ __align__(16) unsigned char plds[2][28672];  // [buf][A 4KB | W 24KB]
    const int tid = threadIdx.x;
    const int w = tid >> 6, lane = tid & 63, r = lane & 15, g = lane >> 4;
    const int row0 = blockIdx.x * 32;
    const int rsel = (w & 1) * 16, csel = (w >> 1) * 96;

    const int srow = tid >> 3, skc = (tid & 7) * 8;   // staging: row, k-offset
    const int sby = (tid & 7) * 16;                   // byte col in LDS row

    f32x4 acc[6];
#pragma unroll
    for (int i = 0; i < 6; ++i) acc[i] = (f32x4){0.f, 0.f, 0.f, 0.f};

    // prologue: stage k-step 0 into buf 0
    {
        const float4* xp = (const float4*)&x[(row0 + srow) * En + skc];
        float4 f0 = xp[0], f1 = xp[1];
        union { bf16x8 v; unsigned u32[4]; } t;
        t.u32[0] = cvtpk(f0.x, f0.y); t.u32[1] = cvtpk(f0.z, f0.w);
        t.u32[2] = cvtpk(f1.x, f1.y); t.u32[3] = cvtpk(f1.z, f1.w);
        *(bf16x8*)&plds[0][srow * 128 + (sby ^ ((srow & 7) << 4))] = t.v;
#pragma unroll
        for (int c2 = 0; c2 < 6; ++c2) {
            const float* Ws = (c2 < 2) ? Wq : ((c2 < 4) ? Wk : Wv);
            int wr = (c2 & 1) * 32 + srow;
            const float4* wp = (const float4*)&Ws[wr * En + skc];
            float4 w0 = wp[0], w1 = wp[1];
            union { bf16x8 v; unsigned u32[4]; } tw;
            tw.u32[0] = cvtpk(w0.x, w0.y); tw.u32[1] = cvtpk(w0.z, w0.w);
            tw.u32[2] = cvtpk(w1.x, w1.y); tw.u32[3] = cvtpk(w1.z, w1.w);
            int wrow = c2 * 32 + srow;
            *(bf16x8*)&plds[0][4096 + wrow * 128 + (sby ^ ((wrow & 7) << 4))] = tw.v;
        }
    }
    __syncthreads();

    for (int s = 0; s < 8; ++s) {
        const int pp = s & 1;
        const bool more = (s < 7);
        // T14: prefetch next k-step into regs (raw fp32 until write phase)
        float4 nf0, nf1;
        float4 nw0[6], nw1[6];
        if (more) {
            int k1 = (s + 1) * 64;
            const float4* xp = (const float4*)&x[(row0 + srow) * En + k1 + skc];
            nf0 = xp[0]; nf1 = xp[1];
#pragma unroll
            for (int c2 = 0; c2 < 6; ++c2) {
                const float* Ws = (c2 < 2) ? Wq : ((c2 < 4) ? Wk : Wv);
                int wr = (c2 & 1) * 32 + srow;
                const float4* wp = (const float4*)&Ws[wr * En + k1 + skc];
                nw0[c2] = wp[0]; nw1[c2] = wp[1];
            }
        }
        // compute from buf pp
        {
            const unsigned char* A = &plds[pp][0];
            const unsigned char* W = &plds[pp][4096];
            int arow = rsel + r, asw = (arow & 7) << 4;
            bf16x8 a0 = *(const bf16x8*)&A[arow * 128 + ((g * 16) ^ asw)];
            bf16x8 a1 = *(const bf16x8*)&A[arow * 128 + ((64 + g * 16) ^ asw)];
#pragma unroll
            for (int ct = 0; ct < 6; ++ct) {
                int wrow = csel + ct * 16 + r, wsw = (wrow & 7) << 4;
                bf16x8 b0 = *(const bf16x8*)&W[wrow * 128 + ((g * 16) ^ wsw)];
                bf16x8 b1 = *(const bf16x8*)&W[wrow * 128 + ((64 + g * 16) ^ wsw)];
                acc[ct] = MFMA16(a0, b0, acc[ct]);
                acc[ct] = MFMA16(a1, b1, acc[ct]);
            }
        }
        // write prefetched tile into buf pp^1, one barrier
        if (more) {
            unsigned char* D = &plds[pp ^ 1][0];
            union { bf16x8 v; unsigned u32[4]; } t;
            t.u32[0] = cvtpk(nf0.x, nf0.y); t.u32[1] = cvtpk(nf0.z, nf0.w);
            t.u32[2] = cvtpk(nf1.x, nf1.y); t.u32[3] = cvtpk(nf1.z, nf1.w);
            *(bf16x8*)&D[srow * 128 + (sby ^ ((srow & 7) << 4))] = t.v;
#pragma unroll
            for (int c2 = 0; c2 < 6; ++c2) {
                union { bf16x8 v; unsigned u32[4]; } tw;
                tw.u32[0] = cvtpk(nw0[c2].x, nw0[c2].y); tw.u32[1] = cvtpk(nw0[c2].z, nw0[c2].w);
                tw.u32[2] = cvtpk(nw1[c2].x, nw1[c2].y); tw.u32[3] = cvtpk(nw1[c2].z, nw1[c2].w);
                int wrow = c2 * 32 + srow;
                *(bf16x8*)&D[4096 + wrow * 128 + (sby ^ ((wrow & 7) << 4))] = tw.v;
            }
        }
        __syncthreads();
    }
    // epilogue: C layout col = lane&15, row = (lane>>4)*4 + reg
#pragma unroll
    for (int ct = 0; ct < 6; ++ct) {
        int n = csel + ct * 16 + r;
#pragma unroll
        for (int reg = 0; reg < 4; ++reg) {
            int gr = row0 + rsel + g * 4 + reg;
            if (n < 64) {
                q16[gr * 64 + n] = f2bf(acc[ct][reg] * QSCALE);
            } else if (n < 128) {
                k16[gr * 64 + (n - 64)] = f2bf(acc[ct][reg]);
            } else {
                int h = n - 128; int bb = gr >> 12; int t = gr & 4095;
                vt16[((bb * 64 + h) << 12) + t] = f2bf(acc[ct][reg]);
            }
        }
    }
}

// ---------------- kernel 2: attention partials (128-q tiles, 8 kv-pieces) ----
// 1024 blocks x 256 thr (4 waves x 32 q-rows [2 qf] = 128-q tile).
// bid -> page=bid>>8 (0..3), idx: s5=idx>>3, b=(idx>>1)&3, q1=idx&1.
// jt = (page&1)? s5 : 31-s5 (every jt hit twice across pages);
// piece = ((page&1)<<2)|((page>>1)<<1)|q1 in 0..7 of nt=2(jt+1) kv64-tiles.
// Per-CU: 4 independent blocks, uniform ~16.5 tiles. vs r18: barriers and
// staging traffic HALVED (128q amortization); K and V frags loaded once per
// tile and reused across both qf. T4 schedule kept: {vmcnt(0); s_barrier;
// issue next DMA; compute} -- prefetch in flight across the (now 2x longer)
// compute phase. Fixed-m log2 softmax; partials (o bf16, l f32) by piece.
__launch_bounds__(256, 4)
__global__ void attnp(const unsigned short* __restrict__ q16, const unsigned short* __restrict__ k16,
                      const unsigned short* __restrict__ vt16,
                      unsigned short* __restrict__ po, float* __restrict__ lp) {
    __shared__ __align__(16) unsigned char lds[2][16384];  // [buf][K 8KB | V 8KB]

    const int tid = threadIdx.x;
    const int w = tid >> 6, lane = tid & 63, r = lane & 15, g = lane >> 4;
    const int bid = blockIdx.x;
    const int page = bid >> 8, idx = bid & 255;
    const int s5 = idx >> 3, b = (idx >> 1) & 3, q1 = idx & 1;
    const int jt = (page & 1) ? s5 : 31 - s5;
    const int piece = ((page & 1) << 2) | ((page >> 1) << 1) | q1;   // 0..7
    const size_t kbase = (size_t)b * Tn;
    const int q0 = jt * 128;
    const int nt = 2 * (jt + 1);                    // kv64 tiles in causal span
    const int t0 = (piece * nt) >> 3;
    const int tEnd = ((piece + 1) * nt) >> 3;
    const int wq0 = q0 + w * 32;                    // wave's 32 q-rows

    const unsigned short* Kb = k16 + kbase * 64;
    const unsigned short* Vb = vt16 + ((size_t)(b * 64) << 12);

    // staging geometry: wave w owns chunks w*4..w*4+3 (1KB each: 8 rows x 128B)
    const int srl = lane >> 3, scb = (lane & 7) * 16;

    // Q B-frags: 2 qf groups of 16 q-rows (pre-scaled into log2 domain)
    bf16x8 bq[2][2];
#pragma unroll
    for (int qf = 0; qf < 2; ++qf) {
        const unsigned short* qp = &q16[(kbase + wq0 + qf * 16 + r) * 64 + g * 8];
        bq[qf][0] = *(const bf16x8*)qp;
        bq[qf][1] = *(const bf16x8*)(qp + 32);
    }

    f32x4 o[2][4];
#pragma unroll
    for (int qf = 0; qf < 2; ++qf)
#pragma unroll
        for (int i = 0; i < 4; ++i) o[qf][i] = (f32x4){0.f, 0.f, 0.f, 0.f};
    float l_[2] = {0.f, 0.f};

    // prologue: issue DMA for tile t0 into buf t0&1
    if (tEnd > t0) {
        int kv0 = t0 * 64;
        unsigned char* D = &lds[t0 & 1][0];
#pragma unroll
        for (int i = 0; i < 4; ++i) {
            int cc = w * 4 + i;
            if (cc < 8) {
                int row = cc * 8 + srl, sw = (row & 7) << 4;
                gl16((const char*)Kb + (size_t)(kv0 + row) * 128 + (scb ^ sw), D + cc * 1024);
            } else {
                int h = (cc - 8) * 8 + srl, sw = (h & 7) << 4;
                gl16((const char*)Vb + (size_t)h * 8192 + (size_t)kv0 * 2 + (scb ^ sw), D + cc * 1024);
            }
        }
    }

    for (int it = t0; it < tEnd; ++it) {
        const int pp = it & 1;
        // T4: wait only for current tile's DMA, raw barrier, then issue next
        asm volatile("s_waitcnt vmcnt(0)" ::: "memory");
        __builtin_amdgcn_s_barrier();
        __builtin_amdgcn_sched_barrier(0);
        if (it + 1 < tEnd) {
            int nkv = (it + 1) * 64;
            unsigned char* D = &lds[pp ^ 1][0];
#pragma unroll
            for (int i = 0; i < 4; ++i) {
                int cc = w * 4 + i;
                if (cc < 8) {
                    int row = cc * 8 + srl, sw = (row & 7) << 4;
                    gl16((const char*)Kb + (size_t)(nkv + row) * 128 + (scb ^ sw), D + cc * 1024);
                } else {
                    int h = (cc - 8) * 8 + srl, sw = (h & 7) << 4;
                    gl16((const char*)Vb + (size_t)h * 8192 + (size_t)nkv * 2 + (scb ^ sw), D + cc * 1024);
                }
            }
        }
        const int kv0 = it * 64;
        if (kv0 <= wq0 + 31) {                      // wave-level causal skip
            const unsigned char* K = &lds[pp][0];
            const unsigned char* V = &lds[pp][8192];
            f32x4 s4[2][4];                          // [qf][ct]
            __builtin_amdgcn_s_setprio(1);
#pragma unroll
            for (int ct = 0; ct < 4; ++ct) {
                int row = ct * 16 + r;
                int base = row * 128, sw = (row & 7) << 4;
                bf16x8 ak0 = *(const bf16x8*)&K[base + ((g * 16) ^ sw)];
                bf16x8 ak1 = *(const bf16x8*)&K[base + ((64 + g * 16) ^ sw)];
#pragma unroll
                for (int qf = 0; qf < 2; ++qf) {
                    f32x4 t = (f32x4){0.f, 0.f, 0.f, 0.f};
                    t = MFMA16(ak0, bq[qf][0], t);
                    t = MFMA16(ak1, bq[qf][1], t);
                    s4[qf][ct] = t;
                }
            }
            __builtin_amdgcn_s_setprio(0);
            // diagonal masking (log2 domain: no scale mul)
            if (kv0 + 63 > wq0) {
#pragma unroll
                for (int qf = 0; qf < 2; ++qf) {
                    int qq = wq0 + qf * 16 + r;
#pragma unroll
                    for (int ct = 0; ct < 4; ++ct)
#pragma unroll
                        for (int reg = 0; reg < 4; ++reg) {
                            int kv = kv0 + ct * 16 + g * 4 + reg;
                            if (kv > qq) s4[qf][ct][reg] = NEGINF;
                        }
                }
            }
            // fixed-m: P = exp2(S); per-lane l partial; pack (no cross-lane ops)
            union { bf16x8 v; unsigned u32[4]; } pk[2][2];
#pragma unroll
            for (int qf = 0; qf < 2; ++qf) {
#pragma unroll
                for (int ct = 0; ct < 4; ++ct)
#pragma unroll
                    for (int reg = 0; reg < 4; ++reg)
                        s4[qf][ct][reg] = exp2fast(s4[qf][ct][reg]);
                l_[qf] += ((s4[qf][0][0] + s4[qf][0][1]) + (s4[qf][0][2] + s4[qf][0][3])) +
                          ((s4[qf][1][0] + s4[qf][1][1]) + (s4[qf][1][2] + s4[qf][1][3])) +
                          ((s4[qf][2][0] + s4[qf][2][1]) + (s4[qf][2][2] + s4[qf][2][3])) +
                          ((s4[qf][3][0] + s4[qf][3][1]) + (s4[qf][3][2] + s4[qf][3][3]));
#pragma unroll
                for (int kf = 0; kf < 2; ++kf) {
                    pk[qf][kf].u32[0] = cvtpk(s4[qf][kf * 2][0], s4[qf][kf * 2][1]);
                    pk[qf][kf].u32[1] = cvtpk(s4[qf][kf * 2][2], s4[qf][kf * 2][3]);
                    pk[qf][kf].u32[2] = cvtpk(s4[qf][kf * 2 + 1][0], s4[qf][kf * 2 + 1][1]);
                    pk[qf][kf].u32[3] = cvtpk(s4[qf][kf * 2 + 1][2], s4[qf][kf * 2 + 1][3]);
                }
            }
            // PV: V frags loaded once, used by BOTH qf
            __builtin_amdgcn_s_setprio(1);
#pragma unroll
            for (int cth = 0; cth < 4; ++cth) {
                int h = cth * 16 + r;
                int vb = h * 128, sw2 = (h & 7) << 4;
#pragma unroll
                for (int kf = 0; kf < 2; ++kf) {
                    int off = kf * 64 + g * 8;
                    union { bf16x8 v; bf16x4 h4[2]; } vv;
                    vv.h4[0] = *(const bf16x4*)&V[vb + (off ^ sw2)];
                    vv.h4[1] = *(const bf16x4*)&V[vb + ((off + 32) ^ sw2)];
                    o[0][cth] = MFMA16(pk[0][kf].v, vv.v, o[0][cth]);
                    o[1][cth] = MFMA16(pk[1][kf].v, vv.v, o[1][cth]);
                }
            }
            __builtin_amdgcn_s_setprio(0);
        }
    }

    // ---- write partials (always; empty piece -> zeros) ----
    const size_t qb = (size_t)piece * 16384 + b * 4096;
#pragma unroll
    for (int qf = 0; qf < 2; ++qf) {
#pragma unroll
        for (int cth = 0; cth < 4; ++cth)
#pragma unroll
            for (int reg = 0; reg < 4; ++reg)
                po[(qb + wq0 + qf * 16 + g * 4 + reg) * 64 + cth * 16 + r] = f2bf(o[qf][cth][reg]);
        lp[(qb + wq0 + qf * 16 + r) * 4 + g] = l_[qf];
    }
}

// ---------------- kernel 3: merge 8 kv-piece partials + normalize ------------
// 512 blocks x 256 thr; thread -> (q, 8 cols): 16B po loads, float4x2 store.
__global__ void merge(const unsigned short* __restrict__ po, const float* __restrict__ lp,
                      float* __restrict__ out) {
    int t = blockIdx.x * 256 + threadIdx.x;        // 0..131071
    int q = t >> 3, c8 = (t & 7) * 8;
    float L = 0.f;
#pragma unroll
    for (int c = 0; c < 8; ++c)
#pragma unroll
        for (int gg = 0; gg < 4; ++gg)
            L += lp[((size_t)c * 16384 + q) * 4 + gg];
    float inv = 1.0f / L;
    float acc[8] = {0.f, 0.f, 0.f, 0.f, 0.f, 0.f, 0.f, 0.f};
#pragma unroll
    for (int c = 0; c < 8; ++c) {
        union { uint4 v; unsigned short u[8]; } ld;
        ld.v = *(const uint4*)&po[((size_t)c * 16384 + q) * 64 + c8];
#pragma unroll
        for (int j = 0; j < 8; ++j) acc[j] += bf2f(ld.u[j]);
    }
    float4* op = (float4*)&out[(size_t)q * 64 + c8];
    op[0] = (float4){acc[0] * inv, acc[1] * inv, acc[2] * inv, acc[3] * inv};
    op[1] = (float4){acc[4] * inv, acc[5] * inv, acc[6] * inv, acc[7] * inv};
}

extern "C" void kernel_launch(void* const* d_in, const int* in_sizes, int n_in,
                              void* d_out, int out_size, void* d_ws, size_t ws_size,
                              hipStream_t stream) {
    const float* x  = (const float*)d_in[0];
    const float* Wq = (const float*)d_in[1];
    const float* Wk = (const float*)d_in[2];
    const float* Wv = (const float*)d_in[3];
    float* out = (float*)d_out;
    char* ws = (char*)d_ws;

    unsigned short* q16 = (unsigned short*)ws;                  // 2 MiB
    unsigned short* k16 = (unsigned short*)(ws + 2097152);      // 2 MiB
    unsigned short* v16 = (unsigned short*)(ws + 4194304);      // 2 MiB
    unsigned short* po  = (unsigned short*)(ws + 6291456);      // 8*16384*64*2 = 16 MiB
    float*          lp  = (float*)(ws + 23068672);              // 8*16384*4*4  = 2 MiB
    // total ws use: ~25 MiB

    hipLaunchKernelGGL(proj, dim3(512), dim3(256), 0, stream, x, Wq, Wk, Wv, q16, k16, v16);
    hipLaunchKernelGGL(attnp, dim3(1024), dim3(256), 0, stream, q16, k16, v16, po, lp);
    hipLaunchKernelGGL(merge, dim3(512), dim3(256), 0, stream, po, lp, out);
}